// Round 1
// baseline (549.041 us; speedup 1.0000x reference)
//
#include <hip/hip_runtime.h>

// Problem: B=512, T=128, C=2000
//   out = (1/B) * sum_b( -inputs[b, min(T,length[b])-1, target[b]] )
// Gather of 512 floats + reduction. Latency/launch-bound; one block, 8 waves.

#define NLL_B 512
#define NLL_T 128
#define NLL_C 2000

__global__ __launch_bounds__(NLL_B)
void NLLSequenceLoss_58832462021143_kernel(const float* __restrict__ inputs,
                                           const int* __restrict__ length,
                                           const int* __restrict__ target,
                                           float* __restrict__ out) {
    const int b = threadIdx.x;  // 0..511, one thread per batch row

    int t = length[b] - 1;
    if (t > NLL_T - 1) t = NLL_T - 1;   // min(T, length) - 1 (defensive; length <= T)
    if (t < 0) t = 0;

    const long long idx = ((long long)b * NLL_T + t) * (long long)NLL_C + target[b];
    float v = -inputs[idx];

    // Wave-level reduction over 64 lanes
    #pragma unroll
    for (int off = 32; off > 0; off >>= 1)
        v += __shfl_down(v, off, 64);

    __shared__ float wsum[NLL_B / 64];
    const int wave = threadIdx.x >> 6;
    const int lane = threadIdx.x & 63;
    if (lane == 0) wsum[wave] = v;
    __syncthreads();

    if (threadIdx.x == 0) {
        float s = 0.0f;
        #pragma unroll
        for (int i = 0; i < NLL_B / 64; ++i) s += wsum[i];
        out[0] = s * (1.0f / (float)NLL_B);
    }
}

extern "C" void kernel_launch(void* const* d_in, const int* in_sizes, int n_in,
                              void* d_out, int out_size, void* d_ws, size_t ws_size,
                              hipStream_t stream) {
    const float* inputs = (const float*)d_in[0];  // [B, T, C] log-probs
    const int*   length = (const int*)d_in[1];    // [B]
    const int*   target = (const int*)d_in[2];    // [B]
    float*       out    = (float*)d_out;          // scalar

    NLLSequenceLoss_58832462021143_kernel<<<1, NLL_B, 0, stream>>>(inputs, length, target, out);
}